// Round 13
// baseline (100.734 us; speedup 1.0000x reference)
//
#include <hip/hip_runtime.h>
#include <hip/hip_bf16.h>

// Problem constants (fixed by setup_inputs): B=64, T=1024, C=768, CK=64, R=256
#define BB 64
#define TT 1024
#define CC 768
#define CKK 64
#define SS 512   // T/2
#define RR 256
#define TOUT 768 // R + S
#define ASTRIDE 68  // 64 + 4 pad: 16B-aligned, stride mod 32 = 4 -> 2-way max
#define NSCORE (BB * 8)        // 512 score blocks
#define TOTROWS (BB * SS)      // 32768 dst-base copy rows
#define K1ROWS 26624           // copy rows in K1 (sized to hide score)
#define NCOPY1 (K1ROWS / 4)    // 6656 copy blocks in K1 (4 rows each)
#define K2ROWS (TOTROWS - K1ROWS)  // 6144 rows in K2
#define NCOPY2 (K2ROWS / 8)    // 768 copy blocks in K2 (8 rows each, 512 thr)

typedef float v4f __attribute__((ext_vector_type(4)));

// dst-base copy of global row rowg (b = rowg/512, d = rowg%512):
// out[b][R+d] = x[b][2d+1]. Temporal x loads (L3 retains for K3 base reads),
// NT stores (out is write-only).
__device__ __forceinline__ void copy_row(const float* __restrict__ x,
                                         float* __restrict__ out,
                                         int rowg, int l) {
  const int b = rowg >> 9;
  const int d = rowg & 511;
  const v4f* s = (const v4f*)(x + ((size_t)b * TT + 2 * d + 1) * CC);
  v4f* dst = (v4f*)(out + ((size_t)b * TOUT + RR + d) * CC);
  v4f a0 = s[l];
  v4f a1 = s[l + 64];
  v4f a2 = s[l + 128];
  __builtin_nontemporal_store(a0, dst + l);
  __builtin_nontemporal_store(a1, dst + l + 64);
  __builtin_nontemporal_store(a2, dst + l + 128);
}

// ---------------------------------------------------------------------------
// Kernel 1 (fused by block range, NO cross-block sync):
//  [0, NSCORE): register-tiled max-GEMM scores[s,d]=dot(k[2s],k[2d+1]);
//    XCD-clustered (blockIdx%8 == batch%8) for B-panel L2 reuse.
//  [NSCORE, NSCORE+NCOPY1): dst-base copy rows [0, K1ROWS), wave per row.
// ---------------------------------------------------------------------------
__global__ __launch_bounds__(256) void score_copy_kernel(
    const float* __restrict__ k, const float* __restrict__ x,
    float* __restrict__ out, unsigned long long* __restrict__ nodekey) {
  const int bid = blockIdx.x;
  const int t = threadIdx.x;

  if (bid >= NSCORE) {
    const int w = t >> 6, l = t & 63;
    copy_row(x, out, (bid - NSCORE) * 4 + w, l);
    return;
  }

  // score path: batch-clustered remap (bijective on [0,512))
  const int low3 = bid & 7;
  const int g = bid >> 3;
  const int rt = g & 7;
  const int b = (g >> 3) * 8 + low3;
  const int tx = t & 15, ty = t >> 4;

  __shared__ float As[64 * ASTRIDE];
  __shared__ float Bs[128 * ASTRIDE];

#pragma unroll
  for (int l = 0; l < 4; ++l) {
    int f = t + l * 256;
    int row = f >> 4, c4 = f & 15;
    float4 va = ((const float4*)(k + ((size_t)b * TT + 2 * (rt * 64 + row)) * CKK))[c4];
    *(float4*)(&As[row * ASTRIDE + c4 * 4]) = va;
  }

  unsigned long long rkey[4];
#pragma unroll
  for (int i = 0; i < 4; ++i) rkey[i] = 0ull;

  for (int ct = 0; ct < 4; ++ct) {
    __syncthreads();
#pragma unroll
    for (int l = 0; l < 8; ++l) {
      int f = t + l * 256;
      int row = f >> 4, c4 = f & 15;
      float4 vb = ((const float4*)(k + ((size_t)b * TT + 2 * (ct * 128 + row) + 1) * CKK))[c4];
      *(float4*)(&Bs[row * ASTRIDE + c4 * 4]) = vb;
    }
    __syncthreads();

    float acc[4][8];
#pragma unroll
    for (int i = 0; i < 4; ++i)
#pragma unroll
      for (int j = 0; j < 8; ++j) acc[i][j] = 0.f;

    for (int k4 = 0; k4 < 16; ++k4) {
      float4 av[4], bv[8];
#pragma unroll
      for (int i = 0; i < 4; ++i)
        av[i] = *(const float4*)(&As[(ty + 16 * i) * ASTRIDE + k4 * 4]);
#pragma unroll
      for (int j = 0; j < 8; ++j)
        bv[j] = *(const float4*)(&Bs[(tx + 16 * j) * ASTRIDE + k4 * 4]);
#pragma unroll
      for (int i = 0; i < 4; ++i)
#pragma unroll
        for (int j = 0; j < 8; ++j) {
          acc[i][j] += av[i].x * bv[j].x;
          acc[i][j] += av[i].y * bv[j].y;
          acc[i][j] += av[i].z * bv[j].z;
          acc[i][j] += av[i].w * bv[j].w;
        }
    }

#pragma unroll
    for (int i = 0; i < 4; ++i) {
      float mx = acc[i][0];
      int mj = 0;
#pragma unroll
      for (int j = 1; j < 8; ++j)
        if (acc[i][j] > mx) { mx = acc[i][j]; mj = j; }  // asc d: > keeps min d
      int d = ct * 128 + tx + 16 * mj;
      unsigned int u = __float_as_uint(mx);
      unsigned int mapped = (u & 0x80000000u) ? ~u : (u | 0x80000000u);
      unsigned long long key =
          ((unsigned long long)mapped << 32) | (unsigned int)(SS - 1 - d);
      if (key > rkey[i]) rkey[i] = key;
    }
  }

#pragma unroll
  for (int i = 0; i < 4; ++i) {
#pragma unroll
    for (int off = 1; off < 16; off <<= 1) {
      unsigned long long o = __shfl_xor(rkey[i], off);
      if (o > rkey[i]) rkey[i] = o;
    }
  }
  if (tx == 0) {
#pragma unroll
    for (int i = 0; i < 4; ++i)
      nodekey[b * SS + rt * 64 + ty + 16 * i] = rkey[i];
  }
}

// ---------------------------------------------------------------------------
// Kernel 2 (fused): blocks [0,64): per-batch stable descending argsort
// (hybrid bitonic) + CSR inversion. Blocks [64, 64+NCOPY2): remaining
// dst-base copy rows — BW-productive work hiding the sort's wall time.
// ---------------------------------------------------------------------------
__global__ __launch_bounds__(512) void sort_copy_kernel(
    const unsigned long long* __restrict__ nodekey,
    int* __restrict__ unm_idx, int* __restrict__ dstinfo,
    int* __restrict__ csr, const float* __restrict__ x,
    float* __restrict__ out) {
  if (blockIdx.x >= BB) {
    const int w = threadIdx.x >> 6, l = threadIdx.x & 63;
    copy_row(x, out, K1ROWS + (blockIdx.x - BB) * 8 + w, l);
    return;
  }

  const int b = blockIdx.x;
  const int i = threadIdx.x;
  const int lane = i & 63, w = i >> 6;
  __shared__ unsigned long long key[SS];
  __shared__ int nodeidx[SS];
  __shared__ int headS[SS];
  __shared__ int nxtS[RR];
  __shared__ int eS[RR];
  __shared__ int wsum[8];

  unsigned long long nk = nodekey[b * SS + i];
  unsigned int mapped;
  int nidx;
  if (i == 0) {  // scores[:,0,:] forced to NEG_INF -> max=-1e30, argmax=0
    mapped = ~__float_as_uint(-1e30f);
    nidx = 0;
  } else {
    mapped = (unsigned int)(nk >> 32);
    nidx = SS - 1 - (int)(nk & 0xffffffffu);
  }
  nodeidx[i] = nidx;
  headS[i] = -1;
  unsigned long long my = ((unsigned long long)(~mapped) << 32) | (unsigned int)i;

  for (int kk = 2; kk <= SS; kk <<= 1) {
    for (int j = kk >> 1; j > 0; j >>= 1) {
      bool up = ((i & kk) == 0);
      bool lower = ((i & j) == 0);
      bool takeMin = (up == lower);
      unsigned long long partner;
      if (j >= 64) {
        key[i] = my;
        __syncthreads();
        partner = key[i ^ j];
        __syncthreads();
      } else {
        partner = __shfl_xor(my, j);
      }
      bool pSmaller = partner < my;
      my = (takeMin == pSmaller) ? partner : my;
    }
  }
  __syncthreads();

  int e = (int)(my & 0xffffffffu);
  if (i < RR) {
    eS[i] = e;
    int d = nodeidx[e];
    nxtS[i] = atomicExch(&headS[d], i);
  } else {
    unm_idx[b * RR + (i - RR)] = e;
  }
  __syncthreads();

  // thread i == dst row d: walk chain, count
  int cnt = 0;
  for (int it = headS[i]; it >= 0; it = nxtS[it]) ++cnt;

  // inclusive scan: wave-level shfl_up, then cross-wave partials
  int v = cnt;
#pragma unroll
  for (int o = 1; o < 64; o <<= 1) {
    int n = __shfl_up(v, o);
    if (lane >= o) v += n;
  }
  if (lane == 63) wsum[w] = v;
  __syncthreads();
  if (i == 0) {
    int run = 0;
    for (int q = 0; q < 8; ++q) { int tmp = wsum[q]; wsum[q] = run; run += tmp; }
  }
  __syncthreads();
  int off = wsum[w] + v - cnt;  // exclusive

  int j = 0;
  for (int it = headS[i]; it >= 0; it = nxtS[it]) csr[b * RR + off + (j++)] = eS[it];
  int e0 = (cnt > 0) ? eS[headS[i]] : 0;
  dstinfo[b * SS + i] = cnt | (e0 << 9) | (off << 18);
}

// ---------------------------------------------------------------------------
// Kernel 3: remainder assembly.
//  blocks [0,512): unm region, 8 rows per wave (32/block): descriptors
//    hoisted (8 adjacent scalar loads), 24 NT loads in flight, then 24 KB
//    contiguous NT store burst. Deep-MLP pure-copy pipeline.
//  blocks [512,4608): chain/dst region, 2 far-paired rows per wave (proven):
//    cnt==0 -> one scalar load; else base from x (temporal, L3-warm) +
//    e0 + CSR extras, all NT.
// ---------------------------------------------------------------------------
__device__ __forceinline__ void chain_row(
    const float* __restrict__ x, const int* __restrict__ dstinfo,
    const int* __restrict__ csr, float* __restrict__ out, int gg, int l) {
  const int b = gg >> 9;
  const int d = gg & 511;
  int info = __builtin_amdgcn_readfirstlane(dstinfo[b * SS + d]);
  int cnt = info & 511;
  if (cnt == 0) return;  // base row already correct from copy
  int e0 = (info >> 9) & 511;
  int off = (info >> 18) & 511;
  v4f* dst = (v4f*)(out + ((size_t)b * TOUT + RR + d) * CC);
  const v4f* s0 = (const v4f*)(x + ((size_t)b * TT + 2 * d + 1) * CC);  // base
  const v4f* s1 = (const v4f*)(x + ((size_t)b * TT + 2 * e0) * CC);
  v4f a0 = s0[l];
  v4f a1 = s0[l + 64];
  v4f a2 = s0[l + 128];
  v4f v0 = __builtin_nontemporal_load(s1 + l);
  v4f v1 = __builtin_nontemporal_load(s1 + l + 64);
  v4f v2 = __builtin_nontemporal_load(s1 + l + 128);
  a0 += v0; a1 += v1; a2 += v2;
  for (int j = 1; j < cnt; ++j) {
    int e = __builtin_amdgcn_readfirstlane(csr[b * RR + off + j]);
    const v4f* s = (const v4f*)(x + ((size_t)b * TT + 2 * e) * CC);
    v4f u0 = __builtin_nontemporal_load(s + l);
    v4f u1 = __builtin_nontemporal_load(s + l + 64);
    v4f u2 = __builtin_nontemporal_load(s + l + 128);
    a0 += u0; a1 += u1; a2 += u2;
  }
  __builtin_nontemporal_store(a0, dst + l);
  __builtin_nontemporal_store(a1, dst + l + 64);
  __builtin_nontemporal_store(a2, dst + l + 128);
}

__global__ __launch_bounds__(256) void gather_kernel(
    const float* __restrict__ x, const int* __restrict__ unm_idx,
    const int* __restrict__ dstinfo, const int* __restrict__ csr,
    float* __restrict__ out) {
  const int w = threadIdx.x >> 6;
  const int l = threadIdx.x & 63;

  if (blockIdx.x < 512) {
    // ---- unm region: 8 rows per wave, deep pipeline ----
    const int base = blockIdx.x * 32 + w * 8;  // 8-row group, never crosses batch
    const int b = base >> 8;
    const int p0 = base & 255;
    const float* xb = x + (size_t)b * TT * CC;
    float* ob = out + ((size_t)b * TOUT + p0) * CC;
    int sr[8];
#pragma unroll
    for (int r = 0; r < 8; ++r)
      sr[r] = 2 * __builtin_amdgcn_readfirstlane(unm_idx[b * RR + p0 + r]);
    v4f a[8][3];
#pragma unroll
    for (int r = 0; r < 8; ++r) {
      const v4f* s = (const v4f*)(xb + (size_t)sr[r] * CC);
      a[r][0] = __builtin_nontemporal_load(s + l);
      a[r][1] = __builtin_nontemporal_load(s + l + 64);
      a[r][2] = __builtin_nontemporal_load(s + l + 128);
    }
#pragma unroll
    for (int r = 0; r < 8; ++r) {
      v4f* dst = (v4f*)(ob + (size_t)r * CC);
      __builtin_nontemporal_store(a[r][0], dst + l);
      __builtin_nontemporal_store(a[r][1], dst + l + 64);
      __builtin_nontemporal_store(a[r][2], dst + l + 128);
    }
  } else {
    // ---- chain/dst region: 2 far-paired rows per wave ----
    const int g = (blockIdx.x - 512) * 4 + w;
    chain_row(x, dstinfo, csr, out, g, l);
    chain_row(x, dstinfo, csr, out, g + 16384, l);
  }
}

extern "C" void kernel_launch(void* const* d_in, const int* in_sizes, int n_in,
                              void* d_out, int out_size, void* d_ws, size_t ws_size,
                              hipStream_t stream) {
  const float* x = (const float*)d_in[0];
  const float* k = (const float*)d_in[1];
  float* out = (float*)d_out;

  char* ws = (char*)d_ws;
  unsigned long long* nodekey = (unsigned long long*)(ws);  // 64*512*8 = 262144
  int* unm_idx = (int*)(ws + 262144);                       // 64*256*4 =  65536
  int* dstinfo = (int*)(ws + 327680);                       // 64*512*4 = 131072
  int* csr     = (int*)(ws + 458752);                       // 64*256*4 =  65536
                                                            // total 524288 B

  score_copy_kernel<<<NSCORE + NCOPY1, 256, 0, stream>>>(k, x, out, nodekey);
  sort_copy_kernel<<<BB + NCOPY2, 512, 0, stream>>>(nodekey, unm_idx, dstinfo,
                                                    csr, x, out);
  gather_kernel<<<4608, 256, 0, stream>>>(x, unm_idx, dstinfo, csr, out);
}

// Round 14
// 95.371 us; speedup vs baseline: 1.0562x; 1.0562x over previous
//
#include <hip/hip_runtime.h>
#include <hip/hip_bf16.h>

// Problem constants (fixed by setup_inputs): B=64, T=1024, C=768, CK=64, R=256
#define BB 64
#define TT 1024
#define CC 768
#define CKK 64
#define SS 512   // T/2
#define RR 256
#define TOUT 768 // R + S
#define ASTRIDE 68  // 64 + 4 pad: 16B-aligned, stride mod 32 = 4 -> 2-way max
#define NSCORE (BB * 8)        // 512 score blocks
#define TOTROWS (BB * SS)      // 32768 dst-base copy rows
#define K1ROWS 26624           // copy rows in K1 (sized to hide score)
#define NCOPY1 (K1ROWS / 4)    // 6656 copy blocks in K1 (4 rows each)
#define K2ROWS (TOTROWS - K1ROWS)  // 6144 rows in K2
#define NCOPY2 (K2ROWS / 8)    // 768 copy blocks in K2 (8 rows each, 512 thr)
#define HALFROWS (BB * TOUT / 2)   // 24576

typedef float v4f __attribute__((ext_vector_type(4)));

// dst-base copy of global row rowg (b = rowg/512, d = rowg%512):
// out[b][R+d] = x[b][2d+1]. Temporal x loads (L3 retains for K3 base reads),
// NT stores (out is write-only).
__device__ __forceinline__ void copy_row(const float* __restrict__ x,
                                         float* __restrict__ out,
                                         int rowg, int l) {
  const int b = rowg >> 9;
  const int d = rowg & 511;
  const v4f* s = (const v4f*)(x + ((size_t)b * TT + 2 * d + 1) * CC);
  v4f* dst = (v4f*)(out + ((size_t)b * TOUT + RR + d) * CC);
  v4f a0 = s[l];
  v4f a1 = s[l + 64];
  v4f a2 = s[l + 128];
  __builtin_nontemporal_store(a0, dst + l);
  __builtin_nontemporal_store(a1, dst + l + 64);
  __builtin_nontemporal_store(a2, dst + l + 128);
}

// ---------------------------------------------------------------------------
// Kernel 1 (fused by block range, NO cross-block sync):
//  [0, NSCORE): register-tiled max-GEMM scores[s,d]=dot(k[2s],k[2d+1]);
//    XCD-clustered (blockIdx%8 == batch%8) for B-panel L2 reuse.
//  [NSCORE, NSCORE+NCOPY1): dst-base copy rows [0, K1ROWS), wave per row.
// ---------------------------------------------------------------------------
__global__ __launch_bounds__(256) void score_copy_kernel(
    const float* __restrict__ k, const float* __restrict__ x,
    float* __restrict__ out, unsigned long long* __restrict__ nodekey) {
  const int bid = blockIdx.x;
  const int t = threadIdx.x;

  if (bid >= NSCORE) {
    const int w = t >> 6, l = t & 63;
    copy_row(x, out, (bid - NSCORE) * 4 + w, l);
    return;
  }

  // score path: batch-clustered remap (bijective on [0,512))
  const int low3 = bid & 7;
  const int g = bid >> 3;
  const int rt = g & 7;
  const int b = (g >> 3) * 8 + low3;
  const int tx = t & 15, ty = t >> 4;

  __shared__ float As[64 * ASTRIDE];
  __shared__ float Bs[128 * ASTRIDE];

#pragma unroll
  for (int l = 0; l < 4; ++l) {
    int f = t + l * 256;
    int row = f >> 4, c4 = f & 15;
    float4 va = ((const float4*)(k + ((size_t)b * TT + 2 * (rt * 64 + row)) * CKK))[c4];
    *(float4*)(&As[row * ASTRIDE + c4 * 4]) = va;
  }

  unsigned long long rkey[4];
#pragma unroll
  for (int i = 0; i < 4; ++i) rkey[i] = 0ull;

  for (int ct = 0; ct < 4; ++ct) {
    __syncthreads();
#pragma unroll
    for (int l = 0; l < 8; ++l) {
      int f = t + l * 256;
      int row = f >> 4, c4 = f & 15;
      float4 vb = ((const float4*)(k + ((size_t)b * TT + 2 * (ct * 128 + row) + 1) * CKK))[c4];
      *(float4*)(&Bs[row * ASTRIDE + c4 * 4]) = vb;
    }
    __syncthreads();

    float acc[4][8];
#pragma unroll
    for (int i = 0; i < 4; ++i)
#pragma unroll
      for (int j = 0; j < 8; ++j) acc[i][j] = 0.f;

    for (int k4 = 0; k4 < 16; ++k4) {
      float4 av[4], bv[8];
#pragma unroll
      for (int i = 0; i < 4; ++i)
        av[i] = *(const float4*)(&As[(ty + 16 * i) * ASTRIDE + k4 * 4]);
#pragma unroll
      for (int j = 0; j < 8; ++j)
        bv[j] = *(const float4*)(&Bs[(tx + 16 * j) * ASTRIDE + k4 * 4]);
#pragma unroll
      for (int i = 0; i < 4; ++i)
#pragma unroll
        for (int j = 0; j < 8; ++j) {
          acc[i][j] += av[i].x * bv[j].x;
          acc[i][j] += av[i].y * bv[j].y;
          acc[i][j] += av[i].z * bv[j].z;
          acc[i][j] += av[i].w * bv[j].w;
        }
    }

#pragma unroll
    for (int i = 0; i < 4; ++i) {
      float mx = acc[i][0];
      int mj = 0;
#pragma unroll
      for (int j = 1; j < 8; ++j)
        if (acc[i][j] > mx) { mx = acc[i][j]; mj = j; }  // asc d: > keeps min d
      int d = ct * 128 + tx + 16 * mj;
      unsigned int u = __float_as_uint(mx);
      unsigned int mapped = (u & 0x80000000u) ? ~u : (u | 0x80000000u);
      unsigned long long key =
          ((unsigned long long)mapped << 32) | (unsigned int)(SS - 1 - d);
      if (key > rkey[i]) rkey[i] = key;
    }
  }

#pragma unroll
  for (int i = 0; i < 4; ++i) {
#pragma unroll
    for (int off = 1; off < 16; off <<= 1) {
      unsigned long long o = __shfl_xor(rkey[i], off);
      if (o > rkey[i]) rkey[i] = o;
    }
  }
  if (tx == 0) {
#pragma unroll
    for (int i = 0; i < 4; ++i)
      nodekey[b * SS + rt * 64 + ty + 16 * i] = rkey[i];
  }
}

// ---------------------------------------------------------------------------
// Kernel 2 (fused): blocks [0,64): per-batch stable descending argsort
// (hybrid bitonic) + CSR inversion. Blocks [64, 64+NCOPY2): remaining
// dst-base copy rows — BW-productive work hiding the sort's wall time.
// ---------------------------------------------------------------------------
__global__ __launch_bounds__(512) void sort_copy_kernel(
    const unsigned long long* __restrict__ nodekey,
    int* __restrict__ unm_idx, int* __restrict__ dstinfo,
    int* __restrict__ csr, const float* __restrict__ x,
    float* __restrict__ out) {
  if (blockIdx.x >= BB) {
    const int w = threadIdx.x >> 6, l = threadIdx.x & 63;
    copy_row(x, out, K1ROWS + (blockIdx.x - BB) * 8 + w, l);
    return;
  }

  const int b = blockIdx.x;
  const int i = threadIdx.x;
  const int lane = i & 63, w = i >> 6;
  __shared__ unsigned long long key[SS];
  __shared__ int nodeidx[SS];
  __shared__ int headS[SS];
  __shared__ int nxtS[RR];
  __shared__ int eS[RR];
  __shared__ int wsum[8];

  unsigned long long nk = nodekey[b * SS + i];
  unsigned int mapped;
  int nidx;
  if (i == 0) {  // scores[:,0,:] forced to NEG_INF -> max=-1e30, argmax=0
    mapped = ~__float_as_uint(-1e30f);
    nidx = 0;
  } else {
    mapped = (unsigned int)(nk >> 32);
    nidx = SS - 1 - (int)(nk & 0xffffffffu);
  }
  nodeidx[i] = nidx;
  headS[i] = -1;
  unsigned long long my = ((unsigned long long)(~mapped) << 32) | (unsigned int)i;

  for (int kk = 2; kk <= SS; kk <<= 1) {
    for (int j = kk >> 1; j > 0; j >>= 1) {
      bool up = ((i & kk) == 0);
      bool lower = ((i & j) == 0);
      bool takeMin = (up == lower);
      unsigned long long partner;
      if (j >= 64) {
        key[i] = my;
        __syncthreads();
        partner = key[i ^ j];
        __syncthreads();
      } else {
        partner = __shfl_xor(my, j);
      }
      bool pSmaller = partner < my;
      my = (takeMin == pSmaller) ? partner : my;
    }
  }
  __syncthreads();

  int e = (int)(my & 0xffffffffu);
  if (i < RR) {
    eS[i] = e;
    int d = nodeidx[e];
    nxtS[i] = atomicExch(&headS[d], i);
  } else {
    unm_idx[b * RR + (i - RR)] = e;
  }
  __syncthreads();

  // thread i == dst row d: walk chain, count
  int cnt = 0;
  for (int it = headS[i]; it >= 0; it = nxtS[it]) ++cnt;

  // inclusive scan: wave-level shfl_up, then cross-wave partials
  int v = cnt;
#pragma unroll
  for (int o = 1; o < 64; o <<= 1) {
    int n = __shfl_up(v, o);
    if (lane >= o) v += n;
  }
  if (lane == 63) wsum[w] = v;
  __syncthreads();
  if (i == 0) {
    int run = 0;
    for (int q = 0; q < 8; ++q) { int tmp = wsum[q]; wsum[q] = run; run += tmp; }
  }
  __syncthreads();
  int off = wsum[w] + v - cnt;  // exclusive

  int j = 0;
  for (int it = headS[i]; it >= 0; it = nxtS[it]) csr[b * RR + off + (j++)] = eS[it];
  int e0 = (cnt > 0) ? eS[headS[i]] : 0;
  dstinfo[b * SS + i] = cnt | (e0 << 9) | (off << 18);
}

// ---------------------------------------------------------------------------
// Kernel 3: remainder assembly (R11/R12-proven). Each wave processes TWO
// distant rows (MLP); 61% of dst slots early-exit on one scalar load.
//  rows [0,R):   out = x[2*unm_idx[p]]                       (NT)
//  rows [R,768): if cnt>0: out = x[2*d+1] + x[2*e0] + extra CSR rows.
//    Base row read from x (temporal, L3-warm from copy); out never read.
// ---------------------------------------------------------------------------
__device__ __forceinline__ void process_row(
    const float* __restrict__ x, const int* __restrict__ unm_idx,
    const int* __restrict__ dstinfo, const int* __restrict__ csr,
    float* __restrict__ out, int pg, int l) {
  const int b = pg / TOUT;
  const int p = pg % TOUT;
  v4f* dst = (v4f*)(out + ((size_t)b * TOUT + p) * CC);

  if (p < RR) {
    int srow = 2 * __builtin_amdgcn_readfirstlane(unm_idx[b * RR + p]);
    const v4f* s = (const v4f*)(x + ((size_t)b * TT + srow) * CC);
    v4f a0 = __builtin_nontemporal_load(s + l);
    v4f a1 = __builtin_nontemporal_load(s + l + 64);
    v4f a2 = __builtin_nontemporal_load(s + l + 128);
    __builtin_nontemporal_store(a0, dst + l);
    __builtin_nontemporal_store(a1, dst + l + 64);
    __builtin_nontemporal_store(a2, dst + l + 128);
  } else {
    int d = p - RR;
    int info = __builtin_amdgcn_readfirstlane(dstinfo[b * SS + d]);
    int cnt = info & 511;
    if (cnt == 0) return;  // base row already correct from copy
    int e0 = (info >> 9) & 511;
    int off = (info >> 18) & 511;
    const v4f* s0 = (const v4f*)(x + ((size_t)b * TT + 2 * d + 1) * CC);  // base
    const v4f* s1 = (const v4f*)(x + ((size_t)b * TT + 2 * e0) * CC);
    v4f a0 = s0[l];
    v4f a1 = s0[l + 64];
    v4f a2 = s0[l + 128];
    v4f v0 = __builtin_nontemporal_load(s1 + l);
    v4f v1 = __builtin_nontemporal_load(s1 + l + 64);
    v4f v2 = __builtin_nontemporal_load(s1 + l + 128);
    a0 += v0; a1 += v1; a2 += v2;
    for (int j = 1; j < cnt; ++j) {
      int e = __builtin_amdgcn_readfirstlane(csr[b * RR + off + j]);
      const v4f* s = (const v4f*)(x + ((size_t)b * TT + 2 * e) * CC);
      v4f u0 = __builtin_nontemporal_load(s + l);
      v4f u1 = __builtin_nontemporal_load(s + l + 64);
      v4f u2 = __builtin_nontemporal_load(s + l + 128);
      a0 += u0; a1 += u1; a2 += u2;
    }
    __builtin_nontemporal_store(a0, dst + l);
    __builtin_nontemporal_store(a1, dst + l + 64);
    __builtin_nontemporal_store(a2, dst + l + 128);
  }
}

__global__ __launch_bounds__(256) void gather_kernel(
    const float* __restrict__ x, const int* __restrict__ unm_idx,
    const int* __restrict__ dstinfo, const int* __restrict__ csr,
    float* __restrict__ out) {
  const int w = threadIdx.x >> 6;
  const int l = threadIdx.x & 63;
  const int r1 = blockIdx.x * 4 + w;
  process_row(x, unm_idx, dstinfo, csr, out, r1, l);
  process_row(x, unm_idx, dstinfo, csr, out, r1 + HALFROWS, l);
}

extern "C" void kernel_launch(void* const* d_in, const int* in_sizes, int n_in,
                              void* d_out, int out_size, void* d_ws, size_t ws_size,
                              hipStream_t stream) {
  const float* x = (const float*)d_in[0];
  const float* k = (const float*)d_in[1];
  float* out = (float*)d_out;

  char* ws = (char*)d_ws;
  unsigned long long* nodekey = (unsigned long long*)(ws);  // 64*512*8 = 262144
  int* unm_idx = (int*)(ws + 262144);                       // 64*256*4 =  65536
  int* dstinfo = (int*)(ws + 327680);                       // 64*512*4 = 131072
  int* csr     = (int*)(ws + 458752);                       // 64*256*4 =  65536
                                                            // total 524288 B

  score_copy_kernel<<<NSCORE + NCOPY1, 256, 0, stream>>>(k, x, out, nodekey);
  sort_copy_kernel<<<BB + NCOPY2, 512, 0, stream>>>(nodekey, unm_idx, dstinfo,
                                                    csr, x, out);
  gather_kernel<<<HALFROWS / 4, 256, 0, stream>>>(x, unm_idx, dstinfo, csr, out);
}